// Round 9
// baseline (500.547 us; speedup 1.0000x reference)
//
#include <hip/hip_runtime.h>
#include <hip/hip_bf16.h>

// Problem constants (B=2, S=2048, E=1024, H=16, d=64)
#define BB 2
#define SS 2048
#define EE 1024
#define HH 16
#define DD 64

using bfrag  = __attribute__((ext_vector_type(8))) short;  // 8 bf16 (4 VGPRs)
using bfrag4 = __attribute__((ext_vector_type(4))) short;  // 4 bf16 (2 VGPRs)
using ffrag  = __attribute__((ext_vector_type(4))) float;  // 4 fp32 accum
using uint2v = __attribute__((ext_vector_type(2))) uint;
using uint4v = __attribute__((ext_vector_type(4))) uint;

#define MFMA32(A, B, C) __builtin_amdgcn_mfma_f32_16x16x32_bf16(A, B, C, 0, 0, 0)
#define MFMA16(A, B, C) __builtin_amdgcn_mfma_f32_16x16x16bf16_1k(A, B, C, 0, 0, 0)

static __device__ __forceinline__ ushort f2bf(float f) {
  __hip_bfloat16 h = __float2bfloat16(f);
  return *reinterpret_cast<ushort*>(&h);
}

// Pack two fp32 -> two bf16 (round-half-up) in 3 VALU ops via v_perm_b32.
// Result: low ushort = lo, high ushort = hi.
static __device__ __forceinline__ uint pack_bf2(float lo, float hi) {
  uint a = __float_as_uint(lo) + 0x8000u;
  uint b = __float_as_uint(hi) + 0x8000u;
  return __builtin_amdgcn_perm(b, a, 0x07060302u);
}

// Async global->LDS, 16 B per lane. LDS dest = wave-uniform base + lane*16.
static __device__ __forceinline__ void gl_lds16(const ushort* g, ushort* l) {
  __builtin_amdgcn_global_load_lds(
      (const __attribute__((address_space(1))) void*)g,
      (__attribute__((address_space(3))) void*)l, 16, 0, 0);
}

// -------------------------------------------------------------------------
// Fused prep: x fp32->bf16 cast (blocks 0..4095) + weight transpose+cast
// (blocks 4096..6271): wq -> wqkvT[0:1024), wo -> woT, wk -> wqkvT[1024:1088),
// wv -> wqkvT[1088:1152). One launch instead of five.
// -------------------------------------------------------------------------
__global__ __launch_bounds__(256) void prep(
    const float* __restrict__ x, const float* __restrict__ wq,
    const float* __restrict__ wk, const float* __restrict__ wv,
    const float* __restrict__ wo, ushort* __restrict__ xb,
    ushort* __restrict__ wqkvT, ushort* __restrict__ woT) {
  __shared__ float t[32][33];
  int id = blockIdx.x;
  if (id < 4096) {  // cast path: 4096*256*4 = 4M elements
    int i = id * 256 + threadIdx.x;
    float4 v = ((const float4*)x)[i];
    ushort4 u = { f2bf(v.x), f2bf(v.y), f2bf(v.z), f2bf(v.w) };
    ((ushort4*)xb)[i] = u;
    return;
  }
  id -= 4096;
  const float* src;
  ushort* dst;
  int N, bx, by;
  if (id < 1024)      { src = wq; dst = wqkvT;                      N = 1024; bx = id & 31;          by = id >> 5; }
  else if (id < 2048) { src = wo; dst = woT;                        N = 1024; bx = (id - 1024) & 31; by = (id - 1024) >> 5; }
  else if (id < 2112) { src = wk; dst = wqkvT + (size_t)1024 * 1024; N = 64;  bx = (id - 2048) & 1;  by = (id - 2048) >> 1; }
  else                { src = wv; dst = wqkvT + (size_t)1088 * 1024; N = 64;  bx = (id - 2112) & 1;  by = (id - 2112) >> 1; }
  const int k0 = by * 32, n0 = bx * 32;
  const int tx = threadIdx.x & 31, ty = threadIdx.x >> 5;  // 32x8
  #pragma unroll
  for (int i = 0; i < 32; i += 8)
    t[ty + i][tx] = src[(size_t)(k0 + ty + i) * N + n0 + tx];
  __syncthreads();
  #pragma unroll
  for (int i = 0; i < 32; i += 8)
    dst[(size_t)(n0 + ty + i) * 1024 + k0 + tx] = f2bf(t[tx][ty + i]);
}

// -------------------------------------------------------------------------
// bf16 MFMA GEMM, 128(M)x64(N) tile, BK=64, 4 waves, wave tile 64x32
// + XCD-aware block swizzle (R8: best measured, kept).
// Dbuf global_load_lds staging, one barrier/iter. XOR-swizzled 16B chunks.
// QKV=true: Bt = [wq|wk|wv]^T (N=1152). Epilogue per n-tile:
//   col<1024 -> Qb (bf16, (acc+bq)*qscale); 1024..1088 -> Kb ([4096x64]);
//   1088..1152 -> VT (bf16, transposed [B][64][S]).
// QKV=false: fp32 out = acc + bias0 (O projection).
// -------------------------------------------------------------------------
template <bool QKV>
__global__ __launch_bounds__(256) void gemm_mfma3(
    const ushort* __restrict__ A, const ushort* __restrict__ Bt,
    const float* __restrict__ bias0, const float* __restrict__ bias1,
    const float* __restrict__ bias2, void* __restrict__ O1,
    ushort* __restrict__ Kb, ushort* __restrict__ VTb,
    int M, int N, int K, float qscale) {
  __shared__ __align__(16) ushort As[2][128 * 64];
  __shared__ __align__(16) ushort Bs[2][64 * 64];
  const int tid = threadIdx.x;
  const int lane = tid & 63;
  const int quad = lane >> 4;
  const int c = lane & 15;
  const int wv = tid >> 6;          // 0..3
  const int wm = (wv & 1) * 64;
  const int wn = (wv >> 1) * 32;

  // XCD-aware swizzle: each XCD gets 4 contiguous m-rows x all n-tiles.
  const int gx = gridDim.x, gy = gridDim.y;
  const int lid = blockIdx.y * gx + blockIdx.x;
  const int xcd = lid & 7;
  const int idx = lid >> 3;
  const int mrow = xcd * (gy >> 3) + idx / gx;
  const int ncol = idx % gx;
  const size_t m0 = (size_t)mrow * 128;
  const size_t n0 = (size_t)ncol * 64;

  const int srow = lane >> 3;             // row within 8-row slab
  const int sck = (lane & 7) ^ srow;      // swizzled chunk (k) within row

  ffrag zero = {0.f, 0.f, 0.f, 0.f};
  ffrag acc[4][2];
  #pragma unroll
  for (int mt = 0; mt < 4; ++mt)
    #pragma unroll
    for (int nt = 0; nt < 2; ++nt) acc[mt][nt] = zero;

  const int NK = K >> 6;
  #pragma unroll
  for (int i = 0; i < 4; ++i) {
    int ia = wv * 4 + i;
    gl_lds16(&A[(m0 + ia * 8 + srow) * (size_t)K + sck * 8], &As[0][ia * 512]);
  }
  #pragma unroll
  for (int i = 0; i < 2; ++i) {
    int ib = wv * 2 + i;
    gl_lds16(&Bt[(n0 + ib * 8 + srow) * (size_t)K + sck * 8], &Bs[0][ib * 512]);
  }
  __syncthreads();

  for (int ki = 0; ki < NK; ++ki) {
    const int buf = ki & 1;
    if (ki + 1 < NK) {
      int k0 = (ki + 1) << 6;
      #pragma unroll
      for (int i = 0; i < 4; ++i) {
        int ia = wv * 4 + i;
        gl_lds16(&A[(m0 + ia * 8 + srow) * (size_t)K + k0 + sck * 8],
                 &As[buf ^ 1][ia * 512]);
      }
      #pragma unroll
      for (int i = 0; i < 2; ++i) {
        int ib = wv * 2 + i;
        gl_lds16(&Bt[(n0 + ib * 8 + srow) * (size_t)K + k0 + sck * 8],
                 &Bs[buf ^ 1][ib * 512]);
      }
    }
    #pragma unroll
    for (int ks = 0; ks < 2; ++ks) {
      bfrag af[4], bf[2];
      #pragma unroll
      for (int mt = 0; mt < 4; ++mt) {
        int ra = wm + mt * 16 + c;
        af[mt] = *(const bfrag*)&As[buf][(ra * 8 + ((ks * 4 + quad) ^ (ra & 7))) * 8];
      }
      #pragma unroll
      for (int nt = 0; nt < 2; ++nt) {
        int rb = wn + nt * 16 + c;
        bf[nt] = *(const bfrag*)&Bs[buf][(rb * 8 + ((ks * 4 + quad) ^ (rb & 7))) * 8];
      }
      #pragma unroll
      for (int mt = 0; mt < 4; ++mt)
        #pragma unroll
        for (int nt = 0; nt < 2; ++nt)
          acc[mt][nt] = MFMA32(af[mt], bf[nt], acc[mt][nt]);
    }
    __syncthreads();
  }

  #pragma unroll
  for (int nt = 0; nt < 2; ++nt) {
    const int colb = (int)n0 + wn + nt * 16;  // multiple of 16
    if (QKV) {
      if (colb < 1024) {         // Q block (pre-scaled bf16)
        float bb = bias0[colb + c];
        ushort* dst = (ushort*)O1 + colb;
        #pragma unroll
        for (int mt = 0; mt < 4; ++mt)
          #pragma unroll
          for (int r = 0; r < 4; ++r) {
            size_t row = m0 + wm + mt * 16 + quad * 4 + r;
            dst[row * 1024 + c] = f2bf((acc[mt][nt][r] + bb) * qscale);
          }
      } else if (colb < 1088) {  // K block -> Kb [4096 x 64]
        float bb = bias1[colb - 1024 + c];
        ushort* dst = Kb + (colb - 1024);
        #pragma unroll
        for (int mt = 0; mt < 4; ++mt)
          #pragma unroll
          for (int r = 0; r < 4; ++r) {
            size_t row = m0 + wm + mt * 16 + quad * 4 + r;
            dst[row * 64 + c] = f2bf(acc[mt][nt][r] + bb);
          }
      } else {                   // V block -> VT [B][64][S] (transposed)
        int d = colb - 1088 + c;
        float bb = bias2[colb - 1088 + c];
        int bidx = (int)(m0 >> 11);
        ushort* dstv = VTb + ((size_t)(bidx * 64 + d)) * SS;
        #pragma unroll
        for (int mt = 0; mt < 4; ++mt) {
          int sb = (int)(m0 & 2047) + wm + mt * 16 + quad * 4;  // 4 consecutive s
          uint2v u;
          u.x = pack_bf2(acc[mt][nt][0] + bb, acc[mt][nt][1] + bb);
          u.y = pack_bf2(acc[mt][nt][2] + bb, acc[mt][nt][3] + bb);
          *(uint2v*)&dstv[sb] = u;
        }
      }
    } else {
      float bb = bias0[colb + c];
      float* dst = (float*)O1;
      #pragma unroll
      for (int mt = 0; mt < 4; ++mt)
        #pragma unroll
        for (int r = 0; r < 4; ++r) {
          size_t row = m0 + wm + mt * 16 + quad * 4 + r;
          dst[row * (size_t)N + colb + c] = acc[mt][nt][r] + bb;
        }
    }
  }
}

// -------------------------------------------------------------------------
// MQA attention v13: OCCUPANCY via KVBLK=32. R8 counters (per-SIMD math):
// MFMA ~13%, VALU ~11%, LDS ~47%, HBM 4%, conflicts 0, Occupancy 33% =>
// latency-bound at 2 blocks/CU (4 waves/SIMD), LDS-capped (64 KB).
// KVBLK 64->32 halves LDS to 34 KB -> 4 blocks/CU = 8 waves/SIMD (cap).
// Key-split reuse structure keeps per-CU LDS traffic unchanged (v9 lesson).
// KV fused in ONE shared array so the fp32 combine overlay (32 KB) stays
// contiguous. Per [half][buf]: [0,2048) = K (32 keys x 64 d, 8-row slabs,
// XOR-chunk swizzle), [2048,4096) = V (64 d x 32 keys, granule = 4 keys,
// phys granule = logical ^ (d&7): reads/writes are 2-way (free)).
// 32 iters/half; per iter: 1 K DMA + 1 V reg-load (16B) per wave, 2 kt
// subtiles (QK^T MFMA32 pair -> exp2 -> pack = PV B-frag -> 4nt MFMA16
// + lsum). Combine: upper waves dump fp32 O^T into retired KV + lsum into
// lbuf; lower waves add, normalize by 1/(ls_lo+ls_hi), store.
// __launch_bounds__(512,8) pins VGPR <= 64 for the 8-wave/SIMD target.
// -------------------------------------------------------------------------
__global__ __launch_bounds__(512, 8) void mqa_attn13(
    const ushort* __restrict__ Q, const ushort* __restrict__ Kg,
    const ushort* __restrict__ VT, ushort* __restrict__ A2) {
  __shared__ __align__(16) ushort KV[2][2][4096];  // [half][buf][K(32x64)|V(64x32)]
  __shared__ float lbuf[512];
  const int tid = threadIdx.x;
  const int lane = tid & 63;
  const int quad = lane >> 4;
  const int c = lane & 15;
  const int wv = tid >> 6;        // 0..7
  const int half = wv >> 2;       // 0: keys [0,1024), 1: [1024,2048)
  const int lw = wv & 3;          // wave-within-half, owns q-tiles lw*2+{0,1}
  const int bid = blockIdx.x;     // [0, 512)
  const int b = bid >> 8;
  const int r = bid & 255;
  const int h = r >> 4;           // 16 blocks per head
  const int s0 = (r & 15) << 7;   // 128 queries per block

  const int srow = lane >> 3;            // row within 8-row slab
  const int sck = (lane & 7) ^ srow;     // swizzled chunk within row (K staging)

  ffrag zero = {0.f, 0.f, 0.f, 0.f};
  bfrag4 ones4;
  #pragma unroll
  for (int i = 0; i < 4; ++i) ones4[i] = (short)16256;  // bf16 1.0

  // Q b-frags: 2 q-tiles x 2 d-halves, held for the whole key loop
  bfrag aq[2][2];
  #pragma unroll
  for (int mt = 0; mt < 2; ++mt) {
    const ushort* qp =
        Q + ((size_t)(b * SS) + s0 + lw * 32 + mt * 16 + c) * EE + h * 64 + quad * 8;
    aq[mt][0] = *(const bfrag*)qp;
    aq[mt][1] = *(const bfrag*)(qp + 32);
  }

  ffrag o[2][4];   // O^T accum: [q-tile][d-tile]
  #pragma unroll
  for (int mt = 0; mt < 2; ++mt)
    #pragma unroll
    for (int nt = 0; nt < 4; ++nt) o[mt][nt] = zero;
  ffrag ls[2] = {zero, zero};

  const int koff = half << 10;    // key offset of this half
  const ushort* Kbase = Kg + (size_t)b * SS * 64;
  const ushort* Vbase = VT + (size_t)b * 64 * SS;
  const int kr = lw * 8 + srow;   // K row staged by this lane (32-key tile)

  // V reg-staging: lane handles row d0, 16B chunk jj (4 chunks x 16 rows/wave)
  const int jj = lane & 3;
  const int d0 = lw * 16 + (lane >> 2);
  const ushort* vsrc = Vbase + (size_t)d0 * SS + jj * 8;
  // swizzled LDS write offsets (ushort idx in V region): phys gran = log ^ (d&7)
  const int q00 = d0 * 32 + (((jj * 2)     ^ (d0 & 7)) * 4);
  const int q01 = d0 * 32 + (((jj * 2 + 1) ^ (d0 & 7)) * 4);

  // ---- prologue: stage tile 0
  {
    uint4v v0 = *(const uint4v*)(vsrc + koff);
    gl_lds16(Kbase + (size_t)(koff + kr) * 64 + sck * 8, &KV[half][0][lw * 512]);
    ushort* vdst = &KV[half][0][2048];
    *(uint2v*)&vdst[q00] = (uint2v){v0[0], v0[1]};
    *(uint2v*)&vdst[q01] = (uint2v){v0[2], v0[3]};
  }
  __syncthreads();

  for (int it = 0; it < 32; ++it) {
    const int buf = it & 1;
    uint4v nv;
    if (it + 1 < 32) {  // early-issue next tile (K via DMA, V to regs)
      int kb = koff + ((it + 1) << 5);
      nv = *(const uint4v*)(vsrc + kb);
      gl_lds16(Kbase + (size_t)(kb + kr) * 64 + sck * 8, &KV[half][buf ^ 1][lw * 512]);
    }
    const ushort* Kt = &KV[half][buf][0];
    const ushort* Vt = &KV[half][buf][2048];

    #pragma unroll
    for (int kt = 0; kt < 2; ++kt) {
      const int key = kt * 16 + c;        // A-frag row (key) for S^T
      const int k7 = key & 7;
      bfrag kf0 = *(const bfrag*)&Kt[(key * 8 + (quad ^ k7)) * 8];
      bfrag kf1 = *(const bfrag*)&Kt[(key * 8 + ((quad + 4) ^ k7)) * 8];
      bfrag4 pb[2];
      #pragma unroll
      for (int mt = 0; mt < 2; ++mt) {
        ffrag st = MFMA32(kf0, aq[mt][0], zero);
        st = MFMA32(kf1, aq[mt][1], st);
        // lane holds S^T[key=kt*16+quad*4+j][q=mt*16+c] for j=0..3
        uint2v uu;
        uu.x = pack_bf2(__builtin_amdgcn_exp2f(st[0]),
                        __builtin_amdgcn_exp2f(st[1]));
        uu.y = pack_bf2(__builtin_amdgcn_exp2f(st[2]),
                        __builtin_amdgcn_exp2f(st[3]));
        pb[mt] = __builtin_bit_cast(bfrag4, uu);   // = PV B-frag, k=quad*4+j
      }
      // PV for this 16-key tile: O^T[d][q] += V^T-frag * P-frag
      const int vg = kt * 4 + quad;       // logical granule (4 keys), 0..7
      #pragma unroll
      for (int nt = 0; nt < 4; ++nt) {
        int d = nt * 16 + c;
        bfrag4 vf = *(const bfrag4*)&Vt[d * 32 + ((vg ^ (d & 7)) * 4)];
        #pragma unroll
        for (int mt = 0; mt < 2; ++mt)
          o[mt][nt] = MFMA16(vf, pb[mt], o[mt][nt]);
      }
      #pragma unroll
      for (int mt = 0; mt < 2; ++mt)
        ls[mt] = MFMA16(ones4, pb[mt], ls[mt]);
    }

    if (it + 1 < 32) {  // swizzled V writes into retired buffer
      ushort* vdst = &KV[half][buf ^ 1][2048];
      *(uint2v*)&vdst[q00] = (uint2v){nv[0], nv[1]};
      *(uint2v*)&vdst[q01] = (uint2v){nv[2], nv[3]};
    }
    __syncthreads();
  }

  // ---- combine halves via retired LDS (KV = 8192 floats; lsums in lbuf)
  float* cbuf = (float*)&KV[0][0][0];
  if (half == 1) {
    float* wb = cbuf + (size_t)lw * 2048;
    #pragma unroll
    for (int mt = 0; mt < 2; ++mt) {
      #pragma unroll
      for (int nt = 0; nt < 4; ++nt)
        *(ffrag*)&wb[(mt * 4 + nt) * 256 + lane * 4] = o[mt][nt];
      lbuf[lw * 128 + mt * 64 + lane] = ls[mt][0];
    }
  }
  __syncthreads();
  if (half == 1) return;

  const float* rb = cbuf + (size_t)lw * 2048;
  #pragma unroll
  for (int mt = 0; mt < 2; ++mt) {
    #pragma unroll
    for (int nt = 0; nt < 4; ++nt) {
      ffrag p = *(const ffrag*)&rb[(mt * 4 + nt) * 256 + lane * 4];
      o[mt][nt] += p;
    }
    const float inv = 1.f / (ls[mt][0] + lbuf[lw * 128 + mt * 64 + lane]);
    const int sp = h * 128 + (s0 >> 4) + lw * 2 + mt;
    ushort* orow = A2 + ((size_t)b * SS + sp) * EE;
    #pragma unroll
    for (int nt = 0; nt < 4; ++nt) {
      uint2v u;
      u.x = pack_bf2(o[mt][nt][0] * inv, o[mt][nt][1] * inv);
      u.y = pack_bf2(o[mt][nt][2] * inv, o[mt][nt][3] * inv);
      *(uint2v*)&orow[c * 64 + nt * 16 + quad * 4] = u;
    }
  }
}

extern "C" void kernel_launch(void* const* d_in, const int* in_sizes, int n_in,
                              void* d_out, int out_size, void* d_ws, size_t ws_size,
                              hipStream_t stream) {
  const float* x  = (const float*)d_in[0];
  const float* wq = (const float*)d_in[1];
  const float* bq = (const float*)d_in[2];
  const float* wk = (const float*)d_in[3];
  const float* bk = (const float*)d_in[4];
  const float* wv = (const float*)d_in[5];
  const float* bv = (const float*)d_in[6];
  const float* wo = (const float*)d_in[7];
  const float* bo = (const float*)d_in[8];
  float* out = (float*)d_out;

  // Workspace layout (bytes)
  char* w = (char*)d_ws;
  ushort* xb     = (ushort*)w;  w += (size_t)4096 * 1024 * 2;  // x bf16
  ushort* wqkvT  = (ushort*)w;  w += (size_t)1152 * 1024 * 2;  // [wq|wk|wv]^T
  ushort* woT    = (ushort*)w;  w += (size_t)1024 * 1024 * 2;  // wo^T bf16
  ushort* Qb     = (ushort*)w;  w += (size_t)4096 * 1024 * 2;  // Q' (pre-scaled)
  ushort* Kb     = (ushort*)w;  w += (size_t)4096 * 64 * 2;    // K bf16 [4096x64]
  ushort* VTb    = (ushort*)w;  w += (size_t)BB * 64 * SS * 2; // V^T bf16
  ushort* A2     = (ushort*)w;  w += (size_t)4096 * 1024 * 2;  // attn (scrambled)

  // Prep: x cast + all weight transposes in one launch
  prep<<<6272, 256, 0, stream>>>(x, wq, wk, wv, wo, xb, wqkvT, woT);

  // Fused QKV projection (V written transposed). Q' scaled by 0.125*log2(e).
  const float qscale = 0.18033688011112042f;  // log2(e)/8
  gemm_mfma3<true><<<dim3(18, 32), 256, 0, stream>>>(
      xb, wqkvT, bq, bk, bv, Qb, Kb, VTb, 4096, 1152, 1024, qscale);

  // Attention: KVBLK=32, 4 blocks/CU (8 waves/SIMD), key split + LDS combine
  mqa_attn13<<<512, 512, 0, stream>>>(Qb, Kb, VTb, A2);

  // Output projection (fp32 out + bias)
  gemm_mfma3<false><<<dim3(16, 32), 256, 0, stream>>>(
      A2, woT, bo, nullptr, nullptr, out, nullptr, nullptr, 4096, 1024, 1024, 1.0f);
}

// Round 10
// 182.655 us; speedup vs baseline: 2.7404x; 2.7404x over previous
//
#include <hip/hip_runtime.h>
#include <hip/hip_bf16.h>

// Problem constants (B=2, S=2048, E=1024, H=16, d=64)
#define BB 2
#define SS 2048
#define EE 1024
#define HH 16
#define DD 64

using bfrag  = __attribute__((ext_vector_type(8))) short;  // 8 bf16 (4 VGPRs)
using bfrag4 = __attribute__((ext_vector_type(4))) short;  // 4 bf16 (2 VGPRs)
using ffrag  = __attribute__((ext_vector_type(4))) float;  // 4 fp32 accum
using uint2v = __attribute__((ext_vector_type(2))) uint;
using uint4v = __attribute__((ext_vector_type(4))) uint;

#define MFMA32(A, B, C) __builtin_amdgcn_mfma_f32_16x16x32_bf16(A, B, C, 0, 0, 0)
#define MFMA16(A, B, C) __builtin_amdgcn_mfma_f32_16x16x16bf16_1k(A, B, C, 0, 0, 0)

static __device__ __forceinline__ ushort f2bf(float f) {
  __hip_bfloat16 h = __float2bfloat16(f);
  return *reinterpret_cast<ushort*>(&h);
}

// Pack two fp32 -> two bf16 (round-half-up) in 3 VALU ops via v_perm_b32.
// Result: low ushort = lo, high ushort = hi.
static __device__ __forceinline__ uint pack_bf2(float lo, float hi) {
  uint a = __float_as_uint(lo) + 0x8000u;
  uint b = __float_as_uint(hi) + 0x8000u;
  return __builtin_amdgcn_perm(b, a, 0x07060302u);
}

// Async global->LDS, 16 B per lane. LDS dest = wave-uniform base + lane*16.
static __device__ __forceinline__ void gl_lds16(const ushort* g, ushort* l) {
  __builtin_amdgcn_global_load_lds(
      (const __attribute__((address_space(1))) void*)g,
      (__attribute__((address_space(3))) void*)l, 16, 0, 0);
}

// -------------------------------------------------------------------------
// Fused prep: x fp32->bf16 cast (blocks 0..4095) + weight transpose+cast
// (blocks 4096..6271): wq -> wqkvT[0:1024), wo -> woT, wk -> wqkvT[1024:1088),
// wv -> wqkvT[1088:1152). One launch instead of five.
// -------------------------------------------------------------------------
__global__ __launch_bounds__(256) void prep(
    const float* __restrict__ x, const float* __restrict__ wq,
    const float* __restrict__ wk, const float* __restrict__ wv,
    const float* __restrict__ wo, ushort* __restrict__ xb,
    ushort* __restrict__ wqkvT, ushort* __restrict__ woT) {
  __shared__ float t[32][33];
  int id = blockIdx.x;
  if (id < 4096) {  // cast path: 4096*256*4 = 4M elements
    int i = id * 256 + threadIdx.x;
    float4 v = ((const float4*)x)[i];
    ushort4 u = { f2bf(v.x), f2bf(v.y), f2bf(v.z), f2bf(v.w) };
    ((ushort4*)xb)[i] = u;
    return;
  }
  id -= 4096;
  const float* src;
  ushort* dst;
  int N, bx, by;
  if (id < 1024)      { src = wq; dst = wqkvT;                      N = 1024; bx = id & 31;          by = id >> 5; }
  else if (id < 2048) { src = wo; dst = woT;                        N = 1024; bx = (id - 1024) & 31; by = (id - 1024) >> 5; }
  else if (id < 2112) { src = wk; dst = wqkvT + (size_t)1024 * 1024; N = 64;  bx = (id - 2048) & 1;  by = (id - 2048) >> 1; }
  else                { src = wv; dst = wqkvT + (size_t)1088 * 1024; N = 64;  bx = (id - 2112) & 1;  by = (id - 2112) >> 1; }
  const int k0 = by * 32, n0 = bx * 32;
  const int tx = threadIdx.x & 31, ty = threadIdx.x >> 5;  // 32x8
  #pragma unroll
  for (int i = 0; i < 32; i += 8)
    t[ty + i][tx] = src[(size_t)(k0 + ty + i) * N + n0 + tx];
  __syncthreads();
  #pragma unroll
  for (int i = 0; i < 32; i += 8)
    dst[(size_t)(n0 + ty + i) * 1024 + k0 + tx] = f2bf(t[tx][ty + i]);
}

// -------------------------------------------------------------------------
// bf16 MFMA GEMM, 128(M)x64(N) tile, BK=64, 4 waves, wave tile 64x32
// + XCD-aware block swizzle (R8: best measured, kept).
// Dbuf global_load_lds staging, one barrier/iter. XOR-swizzled 16B chunks.
// QKV=true: Bt = [wq|wk|wv]^T (N=1152). Epilogue per n-tile:
//   col<1024 -> Qb (bf16, (acc+bq)*qscale); 1024..1088 -> Kb ([4096x64]);
//   1088..1152 -> VT (bf16, transposed [B][64][S]).
// QKV=false: fp32 out = acc + bias0 (O projection).
// -------------------------------------------------------------------------
template <bool QKV>
__global__ __launch_bounds__(256) void gemm_mfma3(
    const ushort* __restrict__ A, const ushort* __restrict__ Bt,
    const float* __restrict__ bias0, const float* __restrict__ bias1,
    const float* __restrict__ bias2, void* __restrict__ O1,
    ushort* __restrict__ Kb, ushort* __restrict__ VTb,
    int M, int N, int K, float qscale) {
  __shared__ __align__(16) ushort As[2][128 * 64];
  __shared__ __align__(16) ushort Bs[2][64 * 64];
  const int tid = threadIdx.x;
  const int lane = tid & 63;
  const int quad = lane >> 4;
  const int c = lane & 15;
  const int wv = tid >> 6;          // 0..3
  const int wm = (wv & 1) * 64;
  const int wn = (wv >> 1) * 32;

  // XCD-aware swizzle: each XCD gets 4 contiguous m-rows x all n-tiles.
  const int gx = gridDim.x, gy = gridDim.y;
  const int lid = blockIdx.y * gx + blockIdx.x;
  const int xcd = lid & 7;
  const int idx = lid >> 3;
  const int mrow = xcd * (gy >> 3) + idx / gx;
  const int ncol = idx % gx;
  const size_t m0 = (size_t)mrow * 128;
  const size_t n0 = (size_t)ncol * 64;

  const int srow = lane >> 3;             // row within 8-row slab
  const int sck = (lane & 7) ^ srow;      // swizzled chunk (k) within row

  ffrag zero = {0.f, 0.f, 0.f, 0.f};
  ffrag acc[4][2];
  #pragma unroll
  for (int mt = 0; mt < 4; ++mt)
    #pragma unroll
    for (int nt = 0; nt < 2; ++nt) acc[mt][nt] = zero;

  const int NK = K >> 6;
  #pragma unroll
  for (int i = 0; i < 4; ++i) {
    int ia = wv * 4 + i;
    gl_lds16(&A[(m0 + ia * 8 + srow) * (size_t)K + sck * 8], &As[0][ia * 512]);
  }
  #pragma unroll
  for (int i = 0; i < 2; ++i) {
    int ib = wv * 2 + i;
    gl_lds16(&Bt[(n0 + ib * 8 + srow) * (size_t)K + sck * 8], &Bs[0][ib * 512]);
  }
  __syncthreads();

  for (int ki = 0; ki < NK; ++ki) {
    const int buf = ki & 1;
    if (ki + 1 < NK) {
      int k0 = (ki + 1) << 6;
      #pragma unroll
      for (int i = 0; i < 4; ++i) {
        int ia = wv * 4 + i;
        gl_lds16(&A[(m0 + ia * 8 + srow) * (size_t)K + k0 + sck * 8],
                 &As[buf ^ 1][ia * 512]);
      }
      #pragma unroll
      for (int i = 0; i < 2; ++i) {
        int ib = wv * 2 + i;
        gl_lds16(&Bt[(n0 + ib * 8 + srow) * (size_t)K + k0 + sck * 8],
                 &Bs[buf ^ 1][ib * 512]);
      }
    }
    #pragma unroll
    for (int ks = 0; ks < 2; ++ks) {
      bfrag af[4], bf[2];
      #pragma unroll
      for (int mt = 0; mt < 4; ++mt) {
        int ra = wm + mt * 16 + c;
        af[mt] = *(const bfrag*)&As[buf][(ra * 8 + ((ks * 4 + quad) ^ (ra & 7))) * 8];
      }
      #pragma unroll
      for (int nt = 0; nt < 2; ++nt) {
        int rb = wn + nt * 16 + c;
        bf[nt] = *(const bfrag*)&Bs[buf][(rb * 8 + ((ks * 4 + quad) ^ (rb & 7))) * 8];
      }
      #pragma unroll
      for (int mt = 0; mt < 4; ++mt)
        #pragma unroll
        for (int nt = 0; nt < 2; ++nt)
          acc[mt][nt] = MFMA32(af[mt], bf[nt], acc[mt][nt]);
    }
    __syncthreads();
  }

  #pragma unroll
  for (int nt = 0; nt < 2; ++nt) {
    const int colb = (int)n0 + wn + nt * 16;  // multiple of 16
    if (QKV) {
      if (colb < 1024) {         // Q block (pre-scaled bf16)
        float bb = bias0[colb + c];
        ushort* dst = (ushort*)O1 + colb;
        #pragma unroll
        for (int mt = 0; mt < 4; ++mt)
          #pragma unroll
          for (int r = 0; r < 4; ++r) {
            size_t row = m0 + wm + mt * 16 + quad * 4 + r;
            dst[row * 1024 + c] = f2bf((acc[mt][nt][r] + bb) * qscale);
          }
      } else if (colb < 1088) {  // K block -> Kb [4096 x 64]
        float bb = bias1[colb - 1024 + c];
        ushort* dst = Kb + (colb - 1024);
        #pragma unroll
        for (int mt = 0; mt < 4; ++mt)
          #pragma unroll
          for (int r = 0; r < 4; ++r) {
            size_t row = m0 + wm + mt * 16 + quad * 4 + r;
            dst[row * 64 + c] = f2bf(acc[mt][nt][r] + bb);
          }
      } else {                   // V block -> VT [B][64][S] (transposed)
        int d = colb - 1088 + c;
        float bb = bias2[colb - 1088 + c];
        int bidx = (int)(m0 >> 11);
        ushort* dstv = VTb + ((size_t)(bidx * 64 + d)) * SS;
        #pragma unroll
        for (int mt = 0; mt < 4; ++mt) {
          int sb = (int)(m0 & 2047) + wm + mt * 16 + quad * 4;  // 4 consecutive s
          uint2v u;
          u.x = pack_bf2(acc[mt][nt][0] + bb, acc[mt][nt][1] + bb);
          u.y = pack_bf2(acc[mt][nt][2] + bb, acc[mt][nt][3] + bb);
          *(uint2v*)&dstv[sb] = u;
        }
      }
    } else {
      float bb = bias0[colb + c];
      float* dst = (float*)O1;
      #pragma unroll
      for (int mt = 0; mt < 4; ++mt)
        #pragma unroll
        for (int r = 0; r < 4; ++r) {
          size_t row = m0 + wm + mt * 16 + quad * 4 + r;
          dst[row * (size_t)N + colb + c] = acc[mt][nt][r] + bb;
        }
    }
  }
}

// -------------------------------------------------------------------------
// MQA attention v14: true occupancy doubling. v13 failed twice over:
// (a) __launch_bounds__(512,8) forced 32 VGPR -> spill storm (FETCH 660MB,
// WRITE 1GB); (b) grid stayed 512 blocks -> residency unchanged anyway.
// v14: 1024 blocks x 64 q, 8 waves, 2-way key split, ONE 16-q tile/wave,
// KVBLK=32 -> LDS 33 KB -> 4 blocks/CU x 8 waves = 8 waves/SIMD (2x v12)
// at IDENTICAL LDS bytes/q (tile-pair 8KB per 16q = 512 B/q = v12 ratio).
// Natural VGPR ~55 (aq[2], o[4], ls) -- no launch-bounds cap.
// Per [half][buf]: KV[0,2048) = K (32k x 64d, 8-row slabs, XOR chunk
// swizzle), [2048,4096) = V^T (64d x 32k, granule=4keys, phys=log^(d&7)).
// 32 iters/half; per iter: 1 K DMA + 1 V 16B reg-load/lane, 2 kt subtiles
// (QK^T MFMA32 pair -> exp2 -> pack = PV B-frag -> 4 nt MFMA16 + lsum).
// All LDS patterns <=2-way per quarter-wave phase (free).
// Combine: upper-half waves dump fp32 O^T (4KB/wave) into retired KV +
// lsum into lbuf; lower waves add, normalize by 1/(ls_lo+ls_hi), store.
// A2 row s' = h*128 + s/16, cols (s%16)*64 + d (b64-vector store).
// -------------------------------------------------------------------------
__global__ __launch_bounds__(512) void mqa_attn14(
    const ushort* __restrict__ Q, const ushort* __restrict__ Kg,
    const ushort* __restrict__ VT, ushort* __restrict__ A2) {
  __shared__ __align__(16) ushort KV[2][2][4096];  // [half][buf][K(32x64)|V(64x32)]
  __shared__ float lbuf[256];
  const int tid = threadIdx.x;
  const int lane = tid & 63;
  const int quad = lane >> 4;
  const int c = lane & 15;
  const int wv = tid >> 6;        // 0..7
  const int half = wv >> 2;       // 0: keys [0,1024), 1: [1024,2048)
  const int lw = wv & 3;          // wave-within-half, owns q-tile lw
  const int bid = blockIdx.x;     // [0, 1024)
  const int b = bid >> 9;
  const int r = bid & 511;
  const int h = r >> 5;           // 32 blocks per head
  const int s0 = (r & 31) << 6;   // 64 queries per block

  const int srow = lane >> 3;            // row within 8-row slab
  const int sck = (lane & 7) ^ srow;     // swizzled chunk within row (K staging)

  ffrag zero = {0.f, 0.f, 0.f, 0.f};
  bfrag4 ones4;
  #pragma unroll
  for (int i = 0; i < 4; ++i) ones4[i] = (short)16256;  // bf16 1.0

  // Q b-frags: 1 q-tile x 2 d-halves, held for the whole key loop
  bfrag aq[2];
  {
    const ushort* qp =
        Q + ((size_t)(b * SS) + s0 + lw * 16 + c) * EE + h * 64 + quad * 8;
    aq[0] = *(const bfrag*)qp;
    aq[1] = *(const bfrag*)(qp + 32);
  }

  ffrag o[4];   // O^T accum: [d-tile]
  #pragma unroll
  for (int nt = 0; nt < 4; ++nt) o[nt] = zero;
  ffrag ls = zero;

  const int koff = half << 10;    // key offset of this half
  const ushort* Kbase = Kg + (size_t)b * SS * 64;
  const ushort* Vbase = VT + (size_t)b * 64 * SS;
  const int kr = lw * 8 + srow;   // K row staged by this lane (32-key tile)

  // V reg-staging: lane handles row d0, 16B chunk jj (4 chunks x 16 rows/wave)
  const int jj = lane & 3;
  const int d0 = lw * 16 + (lane >> 2);
  const ushort* vsrc = Vbase + (size_t)d0 * SS + jj * 8;
  // swizzled LDS write offsets (ushort idx in V region): phys gran = log ^ (d&7)
  const int q00 = d0 * 32 + (((jj * 2)     ^ (d0 & 7)) * 4);
  const int q01 = d0 * 32 + (((jj * 2 + 1) ^ (d0 & 7)) * 4);

  // ---- prologue: stage tile 0
  {
    uint4v v0 = *(const uint4v*)(vsrc + koff);
    gl_lds16(Kbase + (size_t)(koff + kr) * 64 + sck * 8, &KV[half][0][lw * 512]);
    ushort* vdst = &KV[half][0][2048];
    *(uint2v*)&vdst[q00] = (uint2v){v0[0], v0[1]};
    *(uint2v*)&vdst[q01] = (uint2v){v0[2], v0[3]};
  }
  __syncthreads();

  for (int it = 0; it < 32; ++it) {
    const int buf = it & 1;
    uint4v nv;
    if (it + 1 < 32) {  // early-issue next tile (K via DMA, V to regs)
      int kb = koff + ((it + 1) << 5);
      nv = *(const uint4v*)(vsrc + kb);
      gl_lds16(Kbase + (size_t)(kb + kr) * 64 + sck * 8, &KV[half][buf ^ 1][lw * 512]);
    }
    const ushort* Kt = &KV[half][buf][0];
    const ushort* Vt = &KV[half][buf][2048];

    #pragma unroll
    for (int kt = 0; kt < 2; ++kt) {
      const int key = kt * 16 + c;        // A-frag row (key) for S^T
      const int k7 = key & 7;
      bfrag kf0 = *(const bfrag*)&Kt[(key * 8 + (quad ^ k7)) * 8];
      bfrag kf1 = *(const bfrag*)&Kt[(key * 8 + ((quad + 4) ^ k7)) * 8];
      ffrag st = MFMA32(kf0, aq[0], zero);
      st = MFMA32(kf1, aq[1], st);
      // lane holds S^T[key=kt*16+quad*4+j][q=lw*16+c] for j=0..3
      uint2v uu;
      uu.x = pack_bf2(__builtin_amdgcn_exp2f(st[0]),
                      __builtin_amdgcn_exp2f(st[1]));
      uu.y = pack_bf2(__builtin_amdgcn_exp2f(st[2]),
                      __builtin_amdgcn_exp2f(st[3]));
      bfrag4 pb = __builtin_bit_cast(bfrag4, uu);  // = PV B-frag, k=quad*4+j
      // PV for this 16-key tile: O^T[d][q] += V^T-frag * P-frag
      const int vg = kt * 4 + quad;       // logical granule (4 keys), 0..7
      #pragma unroll
      for (int nt = 0; nt < 4; ++nt) {
        int d = nt * 16 + c;
        bfrag4 vf = *(const bfrag4*)&Vt[d * 32 + ((vg ^ (d & 7)) * 4)];
        o[nt] = MFMA16(vf, pb, o[nt]);
      }
      ls = MFMA16(ones4, pb, ls);
    }

    if (it + 1 < 32) {  // swizzled V writes into retired buffer
      ushort* vdst = &KV[half][buf ^ 1][2048];
      *(uint2v*)&vdst[q00] = (uint2v){nv[0], nv[1]};
      *(uint2v*)&vdst[q01] = (uint2v){nv[2], nv[3]};
    }
    __syncthreads();
  }

  // ---- combine halves via retired LDS (KV: 4 waves x 4KB; lsums in lbuf)
  float* cbuf = (float*)&KV[0][0][0];
  if (half == 1) {
    float* wb = cbuf + (size_t)lw * 1024;
    #pragma unroll
    for (int nt = 0; nt < 4; ++nt)
      *(ffrag*)&wb[nt * 256 + lane * 4] = o[nt];
    lbuf[lw * 64 + lane] = ls[0];
  }
  __syncthreads();
  if (half == 1) return;

  const float* rb = cbuf + (size_t)lw * 1024;
  #pragma unroll
  for (int nt = 0; nt < 4; ++nt) {
    ffrag p = *(const ffrag*)&rb[nt * 256 + lane * 4];
    o[nt] += p;
  }
  const float inv = 1.f / (ls[0] + lbuf[lw * 64 + lane]);
  const int sp = h * 128 + (s0 >> 4) + lw;
  ushort* orow = A2 + ((size_t)b * SS + sp) * EE;
  #pragma unroll
  for (int nt = 0; nt < 4; ++nt) {
    uint2v u;
    u.x = pack_bf2(o[nt][0] * inv, o[nt][1] * inv);
    u.y = pack_bf2(o[nt][2] * inv, o[nt][3] * inv);
    *(uint2v*)&orow[c * 64 + nt * 16 + quad * 4] = u;
  }
}

extern "C" void kernel_launch(void* const* d_in, const int* in_sizes, int n_in,
                              void* d_out, int out_size, void* d_ws, size_t ws_size,
                              hipStream_t stream) {
  const float* x  = (const float*)d_in[0];
  const float* wq = (const float*)d_in[1];
  const float* bq = (const float*)d_in[2];
  const float* wk = (const float*)d_in[3];
  const float* bk = (const float*)d_in[4];
  const float* wv = (const float*)d_in[5];
  const float* bv = (const float*)d_in[6];
  const float* wo = (const float*)d_in[7];
  const float* bo = (const float*)d_in[8];
  float* out = (float*)d_out;

  // Workspace layout (bytes)
  char* w = (char*)d_ws;
  ushort* xb     = (ushort*)w;  w += (size_t)4096 * 1024 * 2;  // x bf16
  ushort* wqkvT  = (ushort*)w;  w += (size_t)1152 * 1024 * 2;  // [wq|wk|wv]^T
  ushort* woT    = (ushort*)w;  w += (size_t)1024 * 1024 * 2;  // wo^T bf16
  ushort* Qb     = (ushort*)w;  w += (size_t)4096 * 1024 * 2;  // Q' (pre-scaled)
  ushort* Kb     = (ushort*)w;  w += (size_t)4096 * 64 * 2;    // K bf16 [4096x64]
  ushort* VTb    = (ushort*)w;  w += (size_t)BB * 64 * SS * 2; // V^T bf16
  ushort* A2     = (ushort*)w;  w += (size_t)4096 * 1024 * 2;  // attn (scrambled)

  // Prep: x cast + all weight transposes in one launch
  prep<<<6272, 256, 0, stream>>>(x, wq, wk, wv, wo, xb, wqkvT, woT);

  // Fused QKV projection (V written transposed). Q' scaled by 0.125*log2(e).
  const float qscale = 0.18033688011112042f;  // log2(e)/8
  gemm_mfma3<true><<<dim3(18, 32), 256, 0, stream>>>(
      xb, wqkvT, bq, bk, bv, Qb, Kb, VTb, 4096, 1152, 1024, qscale);

  // Attention: 1024 blocks x 64 q, KVBLK=32, 4 blocks/CU (8 waves/SIMD)
  mqa_attn14<<<1024, 512, 0, stream>>>(Qb, Kb, VTb, A2);

  // Output projection (fp32 out + bias)
  gemm_mfma3<false><<<dim3(16, 32), 256, 0, stream>>>(
      A2, woT, bo, nullptr, nullptr, out, nullptr, nullptr, 4096, 1024, 1024, 1.0f);
}

// Round 11
// 168.731 us; speedup vs baseline: 2.9665x; 1.0825x over previous
//
#include <hip/hip_runtime.h>
#include <hip/hip_bf16.h>

// Problem constants (B=2, S=2048, E=1024, H=16, d=64)
#define BB 2
#define SS 2048
#define EE 1024
#define HH 16
#define DD 64

using bfrag  = __attribute__((ext_vector_type(8))) short;  // 8 bf16 (4 VGPRs)
using bfrag4 = __attribute__((ext_vector_type(4))) short;  // 4 bf16 (2 VGPRs)
using ffrag  = __attribute__((ext_vector_type(4))) float;  // 4 fp32 accum
using uint2v = __attribute__((ext_vector_type(2))) uint;
using uint4v = __attribute__((ext_vector_type(4))) uint;

#define MFMA32(A, B, C) __builtin_amdgcn_mfma_f32_16x16x32_bf16(A, B, C, 0, 0, 0)
#define MFMA16(A, B, C) __builtin_amdgcn_mfma_f32_16x16x16bf16_1k(A, B, C, 0, 0, 0)

static __device__ __forceinline__ ushort f2bf(float f) {
  __hip_bfloat16 h = __float2bfloat16(f);
  return *reinterpret_cast<ushort*>(&h);
}

// Pack two fp32 -> two bf16 (round-half-up) in 3 VALU ops via v_perm_b32.
// Result: low ushort = lo, high ushort = hi.
static __device__ __forceinline__ uint pack_bf2(float lo, float hi) {
  uint a = __float_as_uint(lo) + 0x8000u;
  uint b = __float_as_uint(hi) + 0x8000u;
  return __builtin_amdgcn_perm(b, a, 0x07060302u);
}

// Async global->LDS, 16 B per lane. LDS dest = wave-uniform base + lane*16.
static __device__ __forceinline__ void gl_lds16(const ushort* g, ushort* l) {
  __builtin_amdgcn_global_load_lds(
      (const __attribute__((address_space(1))) void*)g,
      (__attribute__((address_space(3))) void*)l, 16, 0, 0);
}

// -------------------------------------------------------------------------
// Fused prep: x fp32->bf16 cast (blocks 0..4095) + weight transpose+cast
// (blocks 4096..6271): wq -> wqkvT[0:1024), wo -> woT, wk -> wqkvT[1024:1088),
// wv -> wqkvT[1088:1152). One launch instead of five.
// -------------------------------------------------------------------------
__global__ __launch_bounds__(256) void prep(
    const float* __restrict__ x, const float* __restrict__ wq,
    const float* __restrict__ wk, const float* __restrict__ wv,
    const float* __restrict__ wo, ushort* __restrict__ xb,
    ushort* __restrict__ wqkvT, ushort* __restrict__ woT) {
  __shared__ float t[32][33];
  int id = blockIdx.x;
  if (id < 4096) {  // cast path: 4096*256*4 = 4M elements
    int i = id * 256 + threadIdx.x;
    float4 v = ((const float4*)x)[i];
    ushort4 u = { f2bf(v.x), f2bf(v.y), f2bf(v.z), f2bf(v.w) };
    ((ushort4*)xb)[i] = u;
    return;
  }
  id -= 4096;
  const float* src;
  ushort* dst;
  int N, bx, by;
  if (id < 1024)      { src = wq; dst = wqkvT;                      N = 1024; bx = id & 31;          by = id >> 5; }
  else if (id < 2048) { src = wo; dst = woT;                        N = 1024; bx = (id - 1024) & 31; by = (id - 1024) >> 5; }
  else if (id < 2112) { src = wk; dst = wqkvT + (size_t)1024 * 1024; N = 64;  bx = (id - 2048) & 1;  by = (id - 2048) >> 1; }
  else                { src = wv; dst = wqkvT + (size_t)1088 * 1024; N = 64;  bx = (id - 2112) & 1;  by = (id - 2112) >> 1; }
  const int k0 = by * 32, n0 = bx * 32;
  const int tx = threadIdx.x & 31, ty = threadIdx.x >> 5;  // 32x8
  #pragma unroll
  for (int i = 0; i < 32; i += 8)
    t[ty + i][tx] = src[(size_t)(k0 + ty + i) * N + n0 + tx];
  __syncthreads();
  #pragma unroll
  for (int i = 0; i < 32; i += 8)
    dst[(size_t)(n0 + ty + i) * 1024 + k0 + tx] = f2bf(t[tx][ty + i]);
}

// -------------------------------------------------------------------------
// bf16 MFMA GEMM, 128(M)x64(N) tile, BK=64, 4 waves, wave tile 64x32
// + XCD-aware block swizzle (R8 config: session-best measured).
// Dbuf global_load_lds staging, one barrier/iter. XOR-swizzled 16B chunks.
// QKV=true: Bt = [wq|wk|wv]^T (N=1152). Epilogue per n-tile:
//   col<1024 -> Qb (bf16, (acc+bq)*qscale); 1024..1088 -> Kb ([4096x64]);
//   1088..1152 -> VT (bf16, transposed [B][64][S]).
// QKV=false: fp32 out = acc + bias0 (O projection).
// -------------------------------------------------------------------------
template <bool QKV>
__global__ __launch_bounds__(256) void gemm_mfma3(
    const ushort* __restrict__ A, const ushort* __restrict__ Bt,
    const float* __restrict__ bias0, const float* __restrict__ bias1,
    const float* __restrict__ bias2, void* __restrict__ O1,
    ushort* __restrict__ Kb, ushort* __restrict__ VTb,
    int M, int N, int K, float qscale) {
  __shared__ __align__(16) ushort As[2][128 * 64];
  __shared__ __align__(16) ushort Bs[2][64 * 64];
  const int tid = threadIdx.x;
  const int lane = tid & 63;
  const int quad = lane >> 4;
  const int c = lane & 15;
  const int wv = tid >> 6;          // 0..3
  const int wm = (wv & 1) * 64;
  const int wn = (wv >> 1) * 32;

  // XCD-aware swizzle: each XCD gets 4 contiguous m-rows x all n-tiles.
  const int gx = gridDim.x, gy = gridDim.y;
  const int lid = blockIdx.y * gx + blockIdx.x;
  const int xcd = lid & 7;
  const int idx = lid >> 3;
  const int mrow = xcd * (gy >> 3) + idx / gx;
  const int ncol = idx % gx;
  const size_t m0 = (size_t)mrow * 128;
  const size_t n0 = (size_t)ncol * 64;

  const int srow = lane >> 3;             // row within 8-row slab
  const int sck = (lane & 7) ^ srow;      // swizzled chunk (k) within row

  ffrag zero = {0.f, 0.f, 0.f, 0.f};
  ffrag acc[4][2];
  #pragma unroll
  for (int mt = 0; mt < 4; ++mt)
    #pragma unroll
    for (int nt = 0; nt < 2; ++nt) acc[mt][nt] = zero;

  const int NK = K >> 6;
  #pragma unroll
  for (int i = 0; i < 4; ++i) {
    int ia = wv * 4 + i;
    gl_lds16(&A[(m0 + ia * 8 + srow) * (size_t)K + sck * 8], &As[0][ia * 512]);
  }
  #pragma unroll
  for (int i = 0; i < 2; ++i) {
    int ib = wv * 2 + i;
    gl_lds16(&Bt[(n0 + ib * 8 + srow) * (size_t)K + sck * 8], &Bs[0][ib * 512]);
  }
  __syncthreads();

  for (int ki = 0; ki < NK; ++ki) {
    const int buf = ki & 1;
    if (ki + 1 < NK) {
      int k0 = (ki + 1) << 6;
      #pragma unroll
      for (int i = 0; i < 4; ++i) {
        int ia = wv * 4 + i;
        gl_lds16(&A[(m0 + ia * 8 + srow) * (size_t)K + k0 + sck * 8],
                 &As[buf ^ 1][ia * 512]);
      }
      #pragma unroll
      for (int i = 0; i < 2; ++i) {
        int ib = wv * 2 + i;
        gl_lds16(&Bt[(n0 + ib * 8 + srow) * (size_t)K + k0 + sck * 8],
                 &Bs[buf ^ 1][ib * 512]);
      }
    }
    #pragma unroll
    for (int ks = 0; ks < 2; ++ks) {
      bfrag af[4], bf[2];
      #pragma unroll
      for (int mt = 0; mt < 4; ++mt) {
        int ra = wm + mt * 16 + c;
        af[mt] = *(const bfrag*)&As[buf][(ra * 8 + ((ks * 4 + quad) ^ (ra & 7))) * 8];
      }
      #pragma unroll
      for (int nt = 0; nt < 2; ++nt) {
        int rb = wn + nt * 16 + c;
        bf[nt] = *(const bfrag*)&Bs[buf][(rb * 8 + ((ks * 4 + quad) ^ (rb & 7))) * 8];
      }
      #pragma unroll
      for (int mt = 0; mt < 4; ++mt)
        #pragma unroll
        for (int nt = 0; nt < 2; ++nt)
          acc[mt][nt] = MFMA32(af[mt], bf[nt], acc[mt][nt]);
    }
    __syncthreads();
  }

  #pragma unroll
  for (int nt = 0; nt < 2; ++nt) {
    const int colb = (int)n0 + wn + nt * 16;  // multiple of 16
    if (QKV) {
      if (colb < 1024) {         // Q block (pre-scaled bf16)
        float bb = bias0[colb + c];
        ushort* dst = (ushort*)O1 + colb;
        #pragma unroll
        for (int mt = 0; mt < 4; ++mt)
          #pragma unroll
          for (int r = 0; r < 4; ++r) {
            size_t row = m0 + wm + mt * 16 + quad * 4 + r;
            dst[row * 1024 + c] = f2bf((acc[mt][nt][r] + bb) * qscale);
          }
      } else if (colb < 1088) {  // K block -> Kb [4096 x 64]
        float bb = bias1[colb - 1024 + c];
        ushort* dst = Kb + (colb - 1024);
        #pragma unroll
        for (int mt = 0; mt < 4; ++mt)
          #pragma unroll
          for (int r = 0; r < 4; ++r) {
            size_t row = m0 + wm + mt * 16 + quad * 4 + r;
            dst[row * 64 + c] = f2bf(acc[mt][nt][r] + bb);
          }
      } else {                   // V block -> VT [B][64][S] (transposed)
        int d = colb - 1088 + c;
        float bb = bias2[colb - 1088 + c];
        int bidx = (int)(m0 >> 11);
        ushort* dstv = VTb + ((size_t)(bidx * 64 + d)) * SS;
        #pragma unroll
        for (int mt = 0; mt < 4; ++mt) {
          int sb = (int)(m0 & 2047) + wm + mt * 16 + quad * 4;  // 4 consecutive s
          uint2v u;
          u.x = pack_bf2(acc[mt][nt][0] + bb, acc[mt][nt][1] + bb);
          u.y = pack_bf2(acc[mt][nt][2] + bb, acc[mt][nt][3] + bb);
          *(uint2v*)&dstv[sb] = u;
        }
      }
    } else {
      float bb = bias0[colb + c];
      float* dst = (float*)O1;
      #pragma unroll
      for (int mt = 0; mt < 4; ++mt)
        #pragma unroll
        for (int r = 0; r < 4; ++r) {
          size_t row = m0 + wm + mt * 16 + quad * 4 + r;
          dst[row * (size_t)N + colb + c] = acc[mt][nt][r] + bb;
        }
    }
  }
}

// -------------------------------------------------------------------------
// MQA attention v12 (session-best attention: 57 us, SQ_LDS_BANK_CONFLICT=0).
// Block = 8 waves (512 thr), 128 q; waves 0-3 keys [0,1024), waves 4-7
// keys [1024,2048); each wave owns 32 q (2 q-tiles). 512 blocks.
// K: dbuf global_load_lds staging (KVBLK=64: 128B row stride, bijective
// 16-granule chunk swizzle -> conflict-free); V: reg-staged with
// full-granule XOR swizzle (phys granule = logical ^ (d&15)) ->
// conflict-free b64 reads. P stays in registers (exp2 -> pack = PV B-frag).
// lsum via MFMA16(ones,P). Combine halves via retired LDS; normalize by
// 1/(ls_lo+ls_hi). Occupancy note (v9/v12/v14 A/B): MORE waves made this
// kernel SLOWER every time -- it is chain/barrier-bound, not wave-starved.
// -------------------------------------------------------------------------
__global__ __launch_bounds__(512) void mqa_attn12(
    const ushort* __restrict__ Q, const ushort* __restrict__ Kg,
    const ushort* __restrict__ VT, ushort* __restrict__ A2) {
  __shared__ __align__(16) ushort Kt[2][2][4096];  // [half][buf][64k x 64d]
  __shared__ __align__(16) ushort Vt[2][2][4096];  // [half][buf][64d x 16 granules]
  const int tid = threadIdx.x;
  const int lane = tid & 63;
  const int quad = lane >> 4;
  const int c = lane & 15;
  const int wv = tid >> 6;        // 0..7
  const int half = wv >> 2;       // 0: keys [0,1024), 1: [1024,2048)
  const int lw = wv & 3;          // wave-within-half, owns q-tiles lw*2+{0,1}
  const int bid = blockIdx.x;     // [0, 512)
  const int b = bid >> 8;
  const int r = bid & 255;
  const int h = r >> 4;           // 16 blocks per head
  const int s0 = (r & 15) << 7;   // 128 queries per block

  const int srow = lane >> 3;            // row within 8-row slab
  const int sck = (lane & 7) ^ srow;     // swizzled chunk within row (K staging)

  ffrag zero = {0.f, 0.f, 0.f, 0.f};
  bfrag4 ones4;
  #pragma unroll
  for (int i = 0; i < 4; ++i) ones4[i] = (short)16256;  // bf16 1.0

  // Q b-frags: 2 q-tiles x 2 d-halves, held for the whole key loop
  bfrag aq[2][2];
  #pragma unroll
  for (int mt = 0; mt < 2; ++mt) {
    const ushort* qp =
        Q + ((size_t)(b * SS) + s0 + lw * 32 + mt * 16 + c) * EE + h * 64 + quad * 8;
    aq[mt][0] = *(const bfrag*)qp;
    aq[mt][1] = *(const bfrag*)(qp + 32);
  }

  ffrag o[2][4];   // O^T accum: [q-tile][d-tile]
  #pragma unroll
  for (int mt = 0; mt < 2; ++mt)
    #pragma unroll
    for (int nt = 0; nt < 4; ++nt) o[mt][nt] = zero;
  ffrag ls[2] = {zero, zero};

  const int koff = half << 10;    // key offset of this half
  const ushort* Kbase = Kg + (size_t)b * SS * 64;
  const ushort* Vbase = VT + (size_t)b * 64 * SS;
  const int i0 = lw * 2, i1 = lw * 2 + 1;
  const int r0 = i0 * 8 + srow, r1 = i1 * 8 + srow;  // key-rows staged (K)

  // V reg-staging geometry: lane handles rows d0/d1, 16B chunk jj
  const int jj = lane & 7;
  const int d0 = lw * 16 + (lane >> 3);
  const int d1 = d0 + 8;
  const ushort* vsrc0 = Vbase + (size_t)d0 * SS + jj * 8;
  const ushort* vsrc1 = Vbase + (size_t)d1 * SS + jj * 8;
  // swizzled LDS write offsets (ushort idx): phys granule = logical ^ (d&15)
  const int q00 = d0 * 64 + (((jj * 2)     ^ (d0 & 15)) * 4);
  const int q01 = d0 * 64 + (((jj * 2 + 1) ^ (d0 & 15)) * 4);
  const int q10 = d1 * 64 + (((jj * 2)     ^ (d1 & 15)) * 4);
  const int q11 = d1 * 64 + (((jj * 2 + 1) ^ (d1 & 15)) * 4);

  // ---- prologue: stage tile 0
  {
    uint4v v0 = *(const uint4v*)(vsrc0 + koff);
    uint4v v1 = *(const uint4v*)(vsrc1 + koff);
    gl_lds16(Kbase + (size_t)(koff + r0) * 64 + sck * 8, &Kt[half][0][i0 * 512]);
    gl_lds16(Kbase + (size_t)(koff + r1) * 64 + sck * 8, &Kt[half][0][i1 * 512]);
    ushort* vdst = &Vt[half][0][0];
    *(uint2v*)&vdst[q00] = (uint2v){v0[0], v0[1]};
    *(uint2v*)&vdst[q01] = (uint2v){v0[2], v0[3]};
    *(uint2v*)&vdst[q10] = (uint2v){v1[0], v1[1]};
    *(uint2v*)&vdst[q11] = (uint2v){v1[2], v1[3]};
  }
  __syncthreads();

  for (int it = 0; it < 16; ++it) {
    const int buf = it & 1;
    uint4v nv0, nv1;
    if (it + 1 < 16) {  // early-issue next tile (K via DMA, V to regs)
      int kb = koff + ((it + 1) << 6);
      nv0 = *(const uint4v*)(vsrc0 + kb);
      nv1 = *(const uint4v*)(vsrc1 + kb);
      gl_lds16(Kbase + (size_t)(kb + r0) * 64 + sck * 8, &Kt[half][buf ^ 1][i0 * 512]);
      gl_lds16(Kbase + (size_t)(kb + r1) * 64 + sck * 8, &Kt[half][buf ^ 1][i1 * 512]);
    }

    #pragma unroll
    for (int kt = 0; kt < 4; ++kt) {
      const int key = kt * 16 + c;        // A-frag row (key) for S^T
      const int k7 = key & 7;
      bfrag kf0 = *(const bfrag*)&Kt[half][buf][(key * 8 + (quad ^ k7)) * 8];
      bfrag kf1 = *(const bfrag*)&Kt[half][buf][(key * 8 + ((quad + 4) ^ k7)) * 8];
      bfrag4 pb[2];
      #pragma unroll
      for (int mt = 0; mt < 2; ++mt) {
        ffrag st = MFMA32(kf0, aq[mt][0], zero);
        st = MFMA32(kf1, aq[mt][1], st);
        // lane holds S^T[key=kt*16+quad*4+j][q=mt*16+c] for j=0..3
        uint2v uu;
        uu.x = pack_bf2(__builtin_amdgcn_exp2f(st[0]),
                        __builtin_amdgcn_exp2f(st[1]));
        uu.y = pack_bf2(__builtin_amdgcn_exp2f(st[2]),
                        __builtin_amdgcn_exp2f(st[3]));
        pb[mt] = __builtin_bit_cast(bfrag4, uu);   // = PV B-frag, k=quad*4+j
      }
      // PV for this 16-key tile: O^T[d][q] += V^T-frag * P-frag
      const int vg = kt * 4 + quad;       // logical granule (4 keys)
      #pragma unroll
      for (int nt = 0; nt < 4; ++nt) {
        int d = nt * 16 + c;
        bfrag4 vf = *(const bfrag4*)&Vt[half][buf][d * 64 + ((vg ^ c) * 4)];
        #pragma unroll
        for (int mt = 0; mt < 2; ++mt)
          o[mt][nt] = MFMA16(vf, pb[mt], o[mt][nt]);
      }
      #pragma unroll
      for (int mt = 0; mt < 2; ++mt)
        ls[mt] = MFMA16(ones4, pb[mt], ls[mt]);
    }

    if (it + 1 < 16) {  // swizzled V writes into retired buffer
      ushort* vdst = &Vt[half][buf ^ 1][0];
      *(uint2v*)&vdst[q00] = (uint2v){nv0[0], nv0[1]};
      *(uint2v*)&vdst[q01] = (uint2v){nv0[2], nv0[3]};
      *(uint2v*)&vdst[q10] = (uint2v){nv1[0], nv1[1]};
      *(uint2v*)&vdst[q11] = (uint2v){nv1[2], nv1[3]};
    }
    __syncthreads();
  }

  // ---- combine halves via retired LDS (Kt area: 4 waves x 8 KB; Vt: lsums)
  float* cbuf = (float*)&Kt[0][0][0];
  float* lbuf = (float*)&Vt[0][0][0];
  if (half == 1) {
    float* wb = cbuf + (size_t)lw * 2048;
    #pragma unroll
    for (int mt = 0; mt < 2; ++mt) {
      #pragma unroll
      for (int nt = 0; nt < 4; ++nt)
        *(ffrag*)&wb[(mt * 4 + nt) * 256 + lane * 4] = o[mt][nt];
      lbuf[lw * 128 + mt * 64 + lane] = ls[mt][0];
    }
  }
  __syncthreads();
  if (half == 1) return;

  const float* rb = cbuf + (size_t)lw * 2048;
  #pragma unroll
  for (int mt = 0; mt < 2; ++mt) {
    #pragma unroll
    for (int nt = 0; nt < 4; ++nt) {
      ffrag p = *(const ffrag*)&rb[(mt * 4 + nt) * 256 + lane * 4];
      o[mt][nt] += p;
    }
    const float inv = 1.f / (ls[mt][0] + lbuf[lw * 128 + mt * 64 + lane]);
    const int sp = h * 128 + (s0 >> 4) + lw * 2 + mt;
    ushort* orow = A2 + ((size_t)b * SS + sp) * EE;
    #pragma unroll
    for (int nt = 0; nt < 4; ++nt) {
      uint2v u;
      u.x = pack_bf2(o[mt][nt][0] * inv, o[mt][nt][1] * inv);
      u.y = pack_bf2(o[mt][nt][2] * inv, o[mt][nt][3] * inv);
      *(uint2v*)&orow[c * 64 + nt * 16 + quad * 4] = u;
    }
  }
}

extern "C" void kernel_launch(void* const* d_in, const int* in_sizes, int n_in,
                              void* d_out, int out_size, void* d_ws, size_t ws_size,
                              hipStream_t stream) {
  const float* x  = (const float*)d_in[0];
  const float* wq = (const float*)d_in[1];
  const float* bq = (const float*)d_in[2];
  const float* wk = (const float*)d_in[3];
  const float* bk = (const float*)d_in[4];
  const float* wv = (const float*)d_in[5];
  const float* bv = (const float*)d_in[6];
  const float* wo = (const float*)d_in[7];
  const float* bo = (const float*)d_in[8];
  float* out = (float*)d_out;

  // Workspace layout (bytes)
  char* w = (char*)d_ws;
  ushort* xb     = (ushort*)w;  w += (size_t)4096 * 1024 * 2;  // x bf16
  ushort* wqkvT  = (ushort*)w;  w += (size_t)1152 * 1024 * 2;  // [wq|wk|wv]^T
  ushort* woT    = (ushort*)w;  w += (size_t)1024 * 1024 * 2;  // wo^T bf16
  ushort* Qb     = (ushort*)w;  w += (size_t)4096 * 1024 * 2;  // Q' (pre-scaled)
  ushort* Kb     = (ushort*)w;  w += (size_t)4096 * 64 * 2;    // K bf16 [4096x64]
  ushort* VTb    = (ushort*)w;  w += (size_t)BB * 64 * SS * 2; // V^T bf16
  ushort* A2     = (ushort*)w;  w += (size_t)4096 * 1024 * 2;  // attn (scrambled)

  // Prep: x cast + all weight transposes in one launch
  prep<<<6272, 256, 0, stream>>>(x, wq, wk, wv, wo, xb, wqkvT, woT);

  // Fused QKV projection (V written transposed). Q' scaled by 0.125*log2(e).
  const float qscale = 0.18033688011112042f;  // log2(e)/8
  gemm_mfma3<true><<<dim3(18, 32), 256, 0, stream>>>(
      xb, wqkvT, bq, bk, bv, Qb, Kb, VTb, 4096, 1152, 1024, qscale);

  // Attention: 8 waves/block, key split; V reg-staged w/ conflict-free swizzle
  mqa_attn12<<<512, 512, 0, stream>>>(Qb, Kb, VTb, A2);

  // Output projection (fp32 out + bias)
  gemm_mfma3<false><<<dim3(16, 32), 256, 0, stream>>>(
      A2, woT, bo, nullptr, nullptr, out, nullptr, nullptr, 4096, 1024, 1024, 1.0f);
}

// Round 12
// 160.253 us; speedup vs baseline: 3.1235x; 1.0529x over previous
//
#include <hip/hip_runtime.h>
#include <hip/hip_bf16.h>

// Problem constants (B=2, S=2048, E=1024, H=16, d=64)
#define BB 2
#define SS 2048
#define EE 1024
#define HH 16
#define DD 64

using bfrag  = __attribute__((ext_vector_type(8))) short;  // 8 bf16 (4 VGPRs)
using bfrag4 = __attribute__((ext_vector_type(4))) short;  // 4 bf16 (2 VGPRs)
using ffrag  = __attribute__((ext_vector_type(4))) float;  // 4 fp32 accum
using uint2v = __attribute__((ext_vector_type(2))) uint;
using uint4v = __attribute__((ext_vector_type(4))) uint;

#define MFMA32(A, B, C) __builtin_amdgcn_mfma_f32_16x16x32_bf16(A, B, C, 0, 0, 0)

static __device__ __forceinline__ ushort f2bf(float f) {
  __hip_bfloat16 h = __float2bfloat16(f);
  return *reinterpret_cast<ushort*>(&h);
}

// Pack two fp32 -> two bf16 (round-half-up) in 3 VALU ops via v_perm_b32.
static __device__ __forceinline__ uint pack_bf2(float lo, float hi) {
  uint a = __float_as_uint(lo) + 0x8000u;
  uint b = __float_as_uint(hi) + 0x8000u;
  return __builtin_amdgcn_perm(b, a, 0x07060302u);
}

// Async global->LDS, 16 B per lane. LDS dest = wave-uniform base + lane*16.
static __device__ __forceinline__ void gl_lds16(const ushort* g, ushort* l) {
  __builtin_amdgcn_global_load_lds(
      (const __attribute__((address_space(1))) void*)g,
      (__attribute__((address_space(3))) void*)l, 16, 0, 0);
}

// -------------------------------------------------------------------------
// Fused prep: x fp32->bf16 cast (blocks 0..4095) + weight transpose+cast
// (blocks 4096..6271): wq -> wqkvT[0:1024), wo -> woT, wk -> wqkvT[1024:1088),
// wv -> wqkvT[1088:1152). One launch instead of five.
// -------------------------------------------------------------------------
__global__ __launch_bounds__(256) void prep(
    const float* __restrict__ x, const float* __restrict__ wq,
    const float* __restrict__ wk, const float* __restrict__ wv,
    const float* __restrict__ wo, ushort* __restrict__ xb,
    ushort* __restrict__ wqkvT, ushort* __restrict__ woT) {
  __shared__ float t[32][33];
  int id = blockIdx.x;
  if (id < 4096) {  // cast path: 4096*256*4 = 4M elements
    int i = id * 256 + threadIdx.x;
    float4 v = ((const float4*)x)[i];
    ushort4 u = { f2bf(v.x), f2bf(v.y), f2bf(v.z), f2bf(v.w) };
    ((ushort4*)xb)[i] = u;
    return;
  }
  id -= 4096;
  const float* src;
  ushort* dst;
  int N, bx, by;
  if (id < 1024)      { src = wq; dst = wqkvT;                      N = 1024; bx = id & 31;          by = id >> 5; }
  else if (id < 2048) { src = wo; dst = woT;                        N = 1024; bx = (id - 1024) & 31; by = (id - 1024) >> 5; }
  else if (id < 2112) { src = wk; dst = wqkvT + (size_t)1024 * 1024; N = 64;  bx = (id - 2048) & 1;  by = (id - 2048) >> 1; }
  else                { src = wv; dst = wqkvT + (size_t)1088 * 1024; N = 64;  bx = (id - 2112) & 1;  by = (id - 2112) >> 1; }
  const int k0 = by * 32, n0 = bx * 32;
  const int tx = threadIdx.x & 31, ty = threadIdx.x >> 5;  // 32x8
  #pragma unroll
  for (int i = 0; i < 32; i += 8)
    t[ty + i][tx] = src[(size_t)(k0 + ty + i) * N + n0 + tx];
  __syncthreads();
  #pragma unroll
  for (int i = 0; i < 32; i += 8)
    dst[(size_t)(n0 + ty + i) * 1024 + k0 + tx] = f2bf(t[tx][ty + i]);
}

// -------------------------------------------------------------------------
// bf16 MFMA GEMM, 128(M)x64(N) tile, BK=64, 4 waves, wave tile 64x32
// + XCD-aware block swizzle (R8 config: session-best measured).
// Dbuf global_load_lds staging, one barrier/iter. XOR-swizzled 16B chunks.
// QKV=true: Bt = [wq|wk|wv]^T (N=1152). Epilogue per n-tile:
//   col<1024 -> Qb; 1024..1088 -> Kb ([4096x64]); 1088..1152 -> VT
//   (bf16, transposed [B][64][S]) in PV-PERMUTED key order: within each
//   32-key block, pos(t) = ((t>>2)&3)*8 + ((t>>4)&1)*4 + (t&3), so a
//   lane's S^T fragments from two 16-key QK tiles form a 16x16x32 B-frag.
// QKV=false: fp32 out = acc + bias0 (O projection).
// -------------------------------------------------------------------------
template <bool QKV>
__global__ __launch_bounds__(256) void gemm_mfma3(
    const ushort* __restrict__ A, const ushort* __restrict__ Bt,
    const float* __restrict__ bias0, const float* __restrict__ bias1,
    const float* __restrict__ bias2, void* __restrict__ O1,
    ushort* __restrict__ Kb, ushort* __restrict__ VTb,
    int M, int N, int K, float qscale) {
  __shared__ __align__(16) ushort As[2][128 * 64];
  __shared__ __align__(16) ushort Bs[2][64 * 64];
  const int tid = threadIdx.x;
  const int lane = tid & 63;
  const int quad = lane >> 4;
  const int c = lane & 15;
  const int wv = tid >> 6;          // 0..3
  const int wm = (wv & 1) * 64;
  const int wn = (wv >> 1) * 32;

  // XCD-aware swizzle: each XCD gets 4 contiguous m-rows x all n-tiles.
  const int gx = gridDim.x, gy = gridDim.y;
  const int lid = blockIdx.y * gx + blockIdx.x;
  const int xcd = lid & 7;
  const int idx = lid >> 3;
  const int mrow = xcd * (gy >> 3) + idx / gx;
  const int ncol = idx % gx;
  const size_t m0 = (size_t)mrow * 128;
  const size_t n0 = (size_t)ncol * 64;

  const int srow = lane >> 3;             // row within 8-row slab
  const int sck = (lane & 7) ^ srow;      // swizzled chunk (k) within row

  ffrag zero = {0.f, 0.f, 0.f, 0.f};
  ffrag acc[4][2];
  #pragma unroll
  for (int mt = 0; mt < 4; ++mt)
    #pragma unroll
    for (int nt = 0; nt < 2; ++nt) acc[mt][nt] = zero;

  const int NK = K >> 6;
  #pragma unroll
  for (int i = 0; i < 4; ++i) {
    int ia = wv * 4 + i;
    gl_lds16(&A[(m0 + ia * 8 + srow) * (size_t)K + sck * 8], &As[0][ia * 512]);
  }
  #pragma unroll
  for (int i = 0; i < 2; ++i) {
    int ib = wv * 2 + i;
    gl_lds16(&Bt[(n0 + ib * 8 + srow) * (size_t)K + sck * 8], &Bs[0][ib * 512]);
  }
  __syncthreads();

  for (int ki = 0; ki < NK; ++ki) {
    const int buf = ki & 1;
    if (ki + 1 < NK) {
      int k0 = (ki + 1) << 6;
      #pragma unroll
      for (int i = 0; i < 4; ++i) {
        int ia = wv * 4 + i;
        gl_lds16(&A[(m0 + ia * 8 + srow) * (size_t)K + k0 + sck * 8],
                 &As[buf ^ 1][ia * 512]);
      }
      #pragma unroll
      for (int i = 0; i < 2; ++i) {
        int ib = wv * 2 + i;
        gl_lds16(&Bt[(n0 + ib * 8 + srow) * (size_t)K + k0 + sck * 8],
                 &Bs[buf ^ 1][ib * 512]);
      }
    }
    #pragma unroll
    for (int ks = 0; ks < 2; ++ks) {
      bfrag af[4], bf[2];
      #pragma unroll
      for (int mt = 0; mt < 4; ++mt) {
        int ra = wm + mt * 16 + c;
        af[mt] = *(const bfrag*)&As[buf][(ra * 8 + ((ks * 4 + quad) ^ (ra & 7))) * 8];
      }
      #pragma unroll
      for (int nt = 0; nt < 2; ++nt) {
        int rb = wn + nt * 16 + c;
        bf[nt] = *(const bfrag*)&Bs[buf][(rb * 8 + ((ks * 4 + quad) ^ (rb & 7))) * 8];
      }
      #pragma unroll
      for (int mt = 0; mt < 4; ++mt)
        #pragma unroll
        for (int nt = 0; nt < 2; ++nt)
          acc[mt][nt] = MFMA32(af[mt], bf[nt], acc[mt][nt]);
    }
    __syncthreads();
  }

  #pragma unroll
  for (int nt = 0; nt < 2; ++nt) {
    const int colb = (int)n0 + wn + nt * 16;  // multiple of 16
    if (QKV) {
      if (colb < 1024) {         // Q block (pre-scaled bf16)
        float bb = bias0[colb + c];
        ushort* dst = (ushort*)O1 + colb;
        #pragma unroll
        for (int mt = 0; mt < 4; ++mt)
          #pragma unroll
          for (int r = 0; r < 4; ++r) {
            size_t row = m0 + wm + mt * 16 + quad * 4 + r;
            dst[row * 1024 + c] = f2bf((acc[mt][nt][r] + bb) * qscale);
          }
      } else if (colb < 1088) {  // K block -> Kb [4096 x 64]
        float bb = bias1[colb - 1024 + c];
        ushort* dst = Kb + (colb - 1024);
        #pragma unroll
        for (int mt = 0; mt < 4; ++mt)
          #pragma unroll
          for (int r = 0; r < 4; ++r) {
            size_t row = m0 + wm + mt * 16 + quad * 4 + r;
            dst[row * 64 + c] = f2bf(acc[mt][nt][r] + bb);
          }
      } else {                   // V block -> VT permuted [B][64][S]
        int d = colb - 1088 + c;
        float bb = bias2[colb - 1088 + c];
        int bidx = (int)(m0 >> 11);
        ushort* dstv = VTb + ((size_t)(bidx * 64 + d)) * SS;
        #pragma unroll
        for (int mt = 0; mt < 4; ++mt) {
          int sb = (int)(m0 & 2047) + wm + mt * 16 + quad * 4;  // mult of 4
          // PV-permuted position within the 32-key block (4 consecutive)
          int col = (sb & ~31) + ((sb >> 2) & 3) * 8 + ((sb >> 4) & 1) * 4;
          uint2v u;
          u.x = pack_bf2(acc[mt][nt][0] + bb, acc[mt][nt][1] + bb);
          u.y = pack_bf2(acc[mt][nt][2] + bb, acc[mt][nt][3] + bb);
          *(uint2v*)&dstv[col] = u;
        }
      }
    } else {
      float bb = bias0[colb + c];
      float* dst = (float*)O1;
      #pragma unroll
      for (int mt = 0; mt < 4; ++mt)
        #pragma unroll
        for (int r = 0; r < 4; ++r) {
          size_t row = m0 + wm + mt * 16 + quad * 4 + r;
          dst[row * (size_t)N + colb + c] = acc[mt][nt][r] + bb;
        }
    }
  }
}

// -------------------------------------------------------------------------
// MQA attention v15 = v12 structure + PV via K=32 MFMA on permuted keys.
// Keys are a reduction axis: V columns stored in the permuted order above,
// so two 16-key QK^T tiles' S^T fragments concatenate into a 16x16x32
// B-frag (k = quad*8+j). Per 64-key iter: QK 16 MFMA32 (unchanged) + PV
// 16 MFMA32 + 4 lsum MFMA32 (was 32+8 MFMA16) -- 25% less MFMA issue; V
// reads become 8 b128 (was 16 b64); V staging returns to gl_lds16 DMA
// (linear dest, chunk-swizzled GLOBAL source: chunk' = chunk ^ (d&7),
// <=2-way on read = free) -- kills reg-staging VALU + in-loop vmcnt waits.
// Block = 8 waves (512 thr), 128 q; waves 0-3 keys [0,1024), waves 4-7
// keys [1024,2048); each wave owns 32 q (2 q-tiles). 512 blocks.
// Combine halves via retired LDS; normalize by 1/(ls_lo+ls_hi).
// -------------------------------------------------------------------------
__global__ __launch_bounds__(512) void mqa_attn15(
    const ushort* __restrict__ Q, const ushort* __restrict__ Kg,
    const ushort* __restrict__ VT, ushort* __restrict__ A2) {
  __shared__ __align__(16) ushort Kt[2][2][4096];  // [half][buf][64k x 64d]
  __shared__ __align__(16) ushort Vt[2][2][4096];  // [half][buf][64d x 64pos, chunk-swz]
  const int tid = threadIdx.x;
  const int lane = tid & 63;
  const int quad = lane >> 4;
  const int c = lane & 15;
  const int wv = tid >> 6;        // 0..7
  const int half = wv >> 2;       // 0: keys [0,1024), 1: [1024,2048)
  const int lw = wv & 3;          // wave-within-half, owns q-tiles lw*2+{0,1}
  const int bid = blockIdx.x;     // [0, 512)
  const int b = bid >> 8;
  const int r = bid & 255;
  const int h = r >> 4;           // 16 blocks per head
  const int s0 = (r & 15) << 7;   // 128 queries per block

  const int srow = lane >> 3;            // row within 8-row slab
  const int sck = (lane & 7) ^ srow;     // swizzled chunk within row (K staging)

  ffrag zero = {0.f, 0.f, 0.f, 0.f};
  bfrag ones8;
  #pragma unroll
  for (int i = 0; i < 8; ++i) ones8[i] = (short)16256;  // bf16 1.0

  // Q b-frags: 2 q-tiles x 2 d-halves, held for the whole key loop
  bfrag aq[2][2];
  #pragma unroll
  for (int mt = 0; mt < 2; ++mt) {
    const ushort* qp =
        Q + ((size_t)(b * SS) + s0 + lw * 32 + mt * 16 + c) * EE + h * 64 + quad * 8;
    aq[mt][0] = *(const bfrag*)qp;
    aq[mt][1] = *(const bfrag*)(qp + 32);
  }

  ffrag o[2][4];   // O^T accum: [q-tile][d-tile]
  #pragma unroll
  for (int mt = 0; mt < 2; ++mt)
    #pragma unroll
    for (int nt = 0; nt < 4; ++nt) o[mt][nt] = zero;
  ffrag ls[2] = {zero, zero};

  const int koff = half << 10;    // key offset of this half
  const ushort* Kbase = Kg + (size_t)b * SS * 64;
  const ushort* Vbase = VT + (size_t)b * 64 * SS;
  const int i0 = lw * 2, i1 = lw * 2 + 1;
  const int r0 = i0 * 8 + srow, r1 = i1 * 8 + srow;  // key-rows staged (K)

  // V DMA geometry: lane -> (row-in-slab = lane>>3, chunk = lane&7);
  // global source pre-swizzled: chunk' = chunk ^ (d&7); dest linear.
  const int vd0 = lw * 16 + (lane >> 3);       // d row, DMA 0
  const int vd1 = vd0 + 8;                     // d row, DMA 1
  const ushort* vsrc0 = Vbase + (size_t)vd0 * SS + (((lane & 7) ^ (vd0 & 7)) * 8);
  const ushort* vsrc1 = Vbase + (size_t)vd1 * SS + (((lane & 7) ^ (vd1 & 7)) * 8);

  // ---- prologue: stage tile 0 (K + V all via DMA)
  gl_lds16(Kbase + (size_t)(koff + r0) * 64 + sck * 8, &Kt[half][0][i0 * 512]);
  gl_lds16(Kbase + (size_t)(koff + r1) * 64 + sck * 8, &Kt[half][0][i1 * 512]);
  gl_lds16(vsrc0 + koff, &Vt[half][0][(lw * 16) * 64]);
  gl_lds16(vsrc1 + koff, &Vt[half][0][(lw * 16 + 8) * 64]);
  __syncthreads();

  for (int it = 0; it < 16; ++it) {
    const int buf = it & 1;
    if (it + 1 < 16) {  // early-issue next K/V tile (all DMA)
      int kb = koff + ((it + 1) << 6);
      gl_lds16(Kbase + (size_t)(kb + r0) * 64 + sck * 8, &Kt[half][buf ^ 1][i0 * 512]);
      gl_lds16(Kbase + (size_t)(kb + r1) * 64 + sck * 8, &Kt[half][buf ^ 1][i1 * 512]);
      gl_lds16(vsrc0 + kb, &Vt[half][buf ^ 1][(lw * 16) * 64]);
      gl_lds16(vsrc1 + kb, &Vt[half][buf ^ 1][(lw * 16 + 8) * 64]);
    }

    #pragma unroll
    for (int p = 0; p < 2; ++p) {     // 32-key pair-tile
      uint2v uu[2][2];                // [a (16-key subtile)][mt]
      #pragma unroll
      for (int a = 0; a < 2; ++a) {
        const int key = (p * 2 + a) * 16 + c;   // A-frag row (key) for S^T
        const int k7 = key & 7;
        bfrag kf0 = *(const bfrag*)&Kt[half][buf][(key * 8 + (quad ^ k7)) * 8];
        bfrag kf1 = *(const bfrag*)&Kt[half][buf][(key * 8 + ((quad + 4) ^ k7)) * 8];
        #pragma unroll
        for (int mt = 0; mt < 2; ++mt) {
          ffrag st = MFMA32(kf0, aq[mt][0], zero);
          st = MFMA32(kf1, aq[mt][1], st);
          // lane holds S^T[key=(2p+a)*16+quad*4+j][q=mt*16+c], j=0..3
          uu[a][mt].x = pack_bf2(__builtin_amdgcn_exp2f(st[0]),
                                 __builtin_amdgcn_exp2f(st[1]));
          uu[a][mt].y = pack_bf2(__builtin_amdgcn_exp2f(st[2]),
                                 __builtin_amdgcn_exp2f(st[3]));
        }
      }
      // concat -> K=32 B-frag: k = quad*8 + (a*4+j) = permuted V position
      bfrag pb8[2];
      #pragma unroll
      for (int mt = 0; mt < 2; ++mt) {
        uint4v w = {uu[0][mt].x, uu[0][mt].y, uu[1][mt].x, uu[1][mt].y};
        pb8[mt] = __builtin_bit_cast(bfrag, w);
      }
      // PV: O^T[d][q] += V^T-frag(K=32) * P-frag(K=32)
      const int ch = p * 4 + quad;    // logical 16B chunk (8 positions)
      #pragma unroll
      for (int nt = 0; nt < 4; ++nt) {
        int d = nt * 16 + c;
        bfrag vf = *(const bfrag*)&Vt[half][buf][d * 64 + ((ch ^ (d & 7)) * 8)];
        #pragma unroll
        for (int mt = 0; mt < 2; ++mt)
          o[mt][nt] = MFMA32(vf, pb8[mt], o[mt][nt]);
      }
      #pragma unroll
      for (int mt = 0; mt < 2; ++mt)
        ls[mt] = MFMA32(ones8, pb8[mt], ls[mt]);
    }
    __syncthreads();
  }

  // ---- combine halves via retired LDS (Kt area: 4 waves x 8 KB; Vt: lsums)
  float* cbuf = (float*)&Kt[0][0][0];
  float* lbuf = (float*)&Vt[0][0][0];
  if (half == 1) {
    float* wb = cbuf + (size_t)lw * 2048;
    #pragma unroll
    for (int mt = 0; mt < 2; ++mt) {
      #pragma unroll
      for (int nt = 0; nt < 4; ++nt)
        *(ffrag*)&wb[(mt * 4 + nt) * 256 + lane * 4] = o[mt][nt];
      lbuf[lw * 128 + mt * 64 + lane] = ls[mt][0];
    }
  }
  __syncthreads();
  if (half == 1) return;

  const float* rb = cbuf + (size_t)lw * 2048;
  #pragma unroll
  for (int mt = 0; mt < 2; ++mt) {
    #pragma unroll
    for (int nt = 0; nt < 4; ++nt) {
      ffrag pp = *(const ffrag*)&rb[(mt * 4 + nt) * 256 + lane * 4];
      o[mt][nt] += pp;
    }
    const float inv = 1.f / (ls[mt][0] + lbuf[lw * 128 + mt * 64 + lane]);
    const int sp = h * 128 + (s0 >> 4) + lw * 2 + mt;
    ushort* orow = A2 + ((size_t)b * SS + sp) * EE;
    #pragma unroll
    for (int nt = 0; nt < 4; ++nt) {
      uint2v u;
      u.x = pack_bf2(o[mt][nt][0] * inv, o[mt][nt][1] * inv);
      u.y = pack_bf2(o[mt][nt][2] * inv, o[mt][nt][3] * inv);
      *(uint2v*)&orow[c * 64 + nt * 16 + quad * 4] = u;
    }
  }
}

extern "C" void kernel_launch(void* const* d_in, const int* in_sizes, int n_in,
                              void* d_out, int out_size, void* d_ws, size_t ws_size,
                              hipStream_t stream) {
  const float* x  = (const float*)d_in[0];
  const float* wq = (const float*)d_in[1];
  const float* bq = (const float*)d_in[2];
  const float* wk = (const float*)d_in[3];
  const float* bk = (const float*)d_in[4];
  const float* wv = (const float*)d_in[5];
  const float* bv = (const float*)d_in[6];
  const float* wo = (const float*)d_in[7];
  const float* bo = (const float*)d_in[8];
  float* out = (float*)d_out;

  // Workspace layout (bytes)
  char* w = (char*)d_ws;
  ushort* xb     = (ushort*)w;  w += (size_t)4096 * 1024 * 2;  // x bf16
  ushort* wqkvT  = (ushort*)w;  w += (size_t)1152 * 1024 * 2;  // [wq|wk|wv]^T
  ushort* woT    = (ushort*)w;  w += (size_t)1024 * 1024 * 2;  // wo^T bf16
  ushort* Qb     = (ushort*)w;  w += (size_t)4096 * 1024 * 2;  // Q' (pre-scaled)
  ushort* Kb     = (ushort*)w;  w += (size_t)4096 * 64 * 2;    // K bf16 [4096x64]
  ushort* VTb    = (ushort*)w;  w += (size_t)BB * 64 * SS * 2; // V^T bf16 (permuted)
  ushort* A2     = (ushort*)w;  w += (size_t)4096 * 1024 * 2;  // attn (scrambled)

  // Prep: x cast + all weight transposes in one launch
  prep<<<6272, 256, 0, stream>>>(x, wq, wk, wv, wo, xb, wqkvT, woT);

  // Fused QKV projection (V written transposed + PV-permuted).
  const float qscale = 0.18033688011112042f;  // log2(e)/8
  gemm_mfma3<true><<<dim3(18, 32), 256, 0, stream>>>(
      xb, wqkvT, bq, bk, bv, Qb, Kb, VTb, 4096, 1152, 1024, qscale);

  // Attention: v15 -- PV via K=32 MFMA on permuted keys, all-DMA staging
  mqa_attn15<<<512, 512, 0, stream>>>(Qb, Kb, VTb, A2);

  // Output projection (fp32 out + bias)
  gemm_mfma3<false><<<dim3(16, 32), 256, 0, stream>>>(
      A2, woT, bo, nullptr, nullptr, out, nullptr, nullptr, 4096, 1024, 1024, 1.0f);
}